// Round 1
// 161.231 us; speedup vs baseline: 1.0062x; 1.0062x over previous
//
#include <hip/hip_runtime.h>
#include <hip/hip_bf16.h>
#include <math.h>

#define FDIM 6272
#define LQ   256
#define BN   8
#define UDIM 32
#define BL   (BN*LQ)        // 2048
#define WTS  904            // LDS f-stride for staged Wt (16B-aligned, phase-conflict-free)

typedef short  short8 __attribute__((ext_vector_type(8)));
typedef float  f32x4  __attribute__((ext_vector_type(4)));

static __device__ __forceinline__ ushort f2bf(float f) {
    __hip_bfloat16 h = __float2bfloat16(f);
    return *(ushort*)&h;
}
// raw transcendentals (v_exp_f32 = 2^x); s_nop covers the TRANS-op hazard
static __device__ __forceinline__ float fexp2(float x) {
    float r;
    asm volatile("v_exp_f32 %0, %1 \n s_nop 1" : "=v"(r) : "v"(x));
    return r;
}
static __device__ __forceinline__ float frcp(float x) {
    float r;
    asm volatile("v_rcp_f32 %0, %1 \n s_nop 1" : "=v"(r) : "v"(x));
    return r;
}
static __device__ __forceinline__ float tanh_fast(float v) {
    // tanh(v) = 1 - 2/(1 + 2^(2v/ln2))
    return 1.f - 2.f * frcp(1.f + fexp2(v * 2.88539008177793f));
}

// ---------------------------------------------------------------------------
// K1: split-K p = x @ Wt, bf16 MFMA. Wt staged per-block into LDS (bf16,
// [u][f] layout, stride 904) replacing the separate k_wtt kernel. Each
// (bx,by) block writes its f-split partial to pbp[by] with PLAIN stores
// (no atomics -> no pre-zero -> poison-safe). Byproduct: waves 0-1 store
// packed A-frags as xb16[row][f] for K3. grid (64 row-tiles, 7 f-splits).
// ---------------------------------------------------------------------------
__global__ __launch_bounds__(256)
void k1_mfma(const float* __restrict__ x, const float* __restrict__ Wt,
             float* __restrict__ pbp, ushort* __restrict__ xb16) {
    __shared__ ushort wtt_s[UDIM * WTS];   // 56.5 KB -> 2 blocks/CU

    const int t  = threadIdx.x;
    const int f0 = blockIdx.y * 896;

    // --- stage Wt[f0..f0+896][0..32] -> wtt_s[u][f_local] as bf16 ---
    // wave reads 8 full 128B Wt rows per step (fully coalesced, L2-hot)
    {
        const int fl0 = t >> 3;          // 0..31 : f row within step
        const int u4  = (t & 7) * 4;     // 0,4,...,28 : u quad
        #pragma unroll
        for (int s = 0; s < 28; ++s) {
            const int fl = s * 32 + fl0;
            const float4 w4 = *(const float4*)(Wt + (size_t)(f0 + fl) * UDIM + u4);
            wtt_s[(u4 + 0) * WTS + fl] = f2bf(w4.x);
            wtt_s[(u4 + 1) * WTS + fl] = f2bf(w4.y);
            wtt_s[(u4 + 2) * WTS + fl] = f2bf(w4.z);
            wtt_s[(u4 + 3) * WTS + fl] = f2bf(w4.w);
        }
    }
    __syncthreads();

    const int wv   = t >> 6, lane = t & 63;
    const int n16  = lane & 15, quad = lane >> 4;
    const int row0 = blockIdx.x * 32 + 16 * (wv & 1);
    const int u0   = 16 * (wv >> 1);

    const float*  xr = x + (size_t)(row0 + n16) * FDIM + f0 + quad * 8;
    const ushort* wr = wtt_s + (u0 + n16) * WTS + quad * 8;
    ushort*       xw = xb16 + (size_t)(row0 + n16) * FDIM + f0 + quad * 8;

    f32x4 acc = (f32x4){0.f, 0.f, 0.f, 0.f};

    #pragma unroll 4
    for (int c = 0; c < 28; ++c) {
        const float4 a0 = *(const float4*)(xr + c * 32);
        const float4 a1 = *(const float4*)(xr + c * 32 + 4);
        short8 af;
        af[0] = (short)f2bf(a0.x); af[1] = (short)f2bf(a0.y);
        af[2] = (short)f2bf(a0.z); af[3] = (short)f2bf(a0.w);
        af[4] = (short)f2bf(a1.x); af[5] = (short)f2bf(a1.y);
        af[6] = (short)f2bf(a1.z); af[7] = (short)f2bf(a1.w);
        if (wv < 2)                         // waves 2,3 duplicate rows: skip
            *(short8*)(xw + c * 32) = af;
        const short8 bf = *(const short8*)(wr + c * 32);  // ds_read_b128
        acc = __builtin_amdgcn_mfma_f32_16x16x32_bf16(af, bf, acc, 0, 0, 0);
    }

    // plain stores: pbp[by][row][u], each element written exactly once
    float* pb = pbp + (size_t)blockIdx.y * BL * UDIM;
    #pragma unroll
    for (int r = 0; r < 4; ++r)
        pb[(size_t)(row0 + quad * 4 + r) * UDIM + u0 + n16] = acc[r];
}

// ---------------------------------------------------------------------------
// K2: a[b,q,:] = softmax_k sigmoid( tanh(p_q+p_k+bh).Wa + ba ), fast-tanh.
// Sums the 7 split-K partials on load (float4, L2-hot), then amortizes the
// 32KB pk tile over 4 q-rows per block. grid 512 (8 b x 64 q-tiles).
// ---------------------------------------------------------------------------
__global__ __launch_bounds__(256)
void k2_attn(const float* __restrict__ pbp, const float* __restrict__ bh,
             const float* __restrict__ Wa, const float* __restrict__ ba,
             ushort* __restrict__ ab) {
    const int blk = blockIdx.x;
    const int b   = blk >> 6, qt = blk & 63;   // 4 q-rows per block
    const int k   = threadIdx.x;

    __shared__ float pk_s[LQ * 33];
    __shared__ float pq_s[4][UDIM];
    __shared__ float wa_s[UDIM];
    __shared__ float red[4][4];

    if (k < UDIM) wa_s[k] = Wa[k];
    const float* pbb = pbp + (size_t)b * LQ * UDIM;
    #pragma unroll
    for (int i = 0; i < 8; ++i) {              // sum 7 partials, float4
        const int e = 4 * k + 1024 * i;        // element in [0, 8192)
        float4 v = *(const float4*)(pbb + e);
        #pragma unroll
        for (int y = 1; y < 7; ++y) {
            const float4 p = *(const float4*)(pbb + (size_t)y * BL * UDIM + e);
            v.x += p.x; v.y += p.y; v.z += p.z; v.w += p.w;
        }
        float* d = &pk_s[(e >> 5) * 33 + (e & 31)];  // same 33-stride swizzle
        d[0] = v.x; d[1] = v.y; d[2] = v.z; d[3] = v.w;
    }
    __syncthreads();
    if (k < 4 * UDIM) {
        const int j = k >> 5, u = k & 31;
        pq_s[j][u] = pk_s[(qt * 4 + j) * 33 + u] + bh[u];
    }
    __syncthreads();

    // cache this thread's k-row once, reuse for 4 q's (32 VGPRs)
    const float* pk = &pk_s[k * 33];
    float pkr[UDIM];
    #pragma unroll
    for (int u = 0; u < UDIM; ++u) pkr[u] = pk[u];

    const float ba0 = ba[0];
    float e4[4];
    #pragma unroll
    for (int j = 0; j < 4; ++j) {
        float s = 0.f;
        #pragma unroll
        for (int u = 0; u < UDIM; ++u)
            s = fmaf(tanh_fast(pq_s[j][u] + pkr[u]), wa_s[u], s);

        const float alpha = frcp(1.f + fexp2(-(s + ba0) * 1.44269504088896f));
        const float e = fexp2(alpha * 1.44269504088896f);  // sigmoid in (0,1): safe
        e4[j] = e;

        float v = e;
        #pragma unroll
        for (int m = 1; m < 64; m <<= 1) v += __shfl_xor(v, m, 64);
        if ((k & 63) == 0) red[j][k >> 6] = v;
    }
    __syncthreads();
    #pragma unroll
    for (int j = 0; j < 4; ++j) {
        const float tot = red[j][0] + red[j][1] + red[j][2] + red[j][3];
        ab[((size_t)b * LQ + qt * 4 + j) * LQ + k] = f2bf(e4[j] * frcp(tot));
    }
}

// ---------------------------------------------------------------------------
// K3: out[b,q,f] = sum_k a[b,q,k]*x[b,k,f], bf16 MFMA, staging from xb16
// (bf16: half the fetch bytes, no v_cvt in repack). BK=64 double-
// buffered LDS, one barrier per chunk, prefetch in flight across barrier.
// A-frags direct from global (ab is L2-hot). Bs rows stride 72 ushort
// (9x16B, odd -> conflict-free b128 frags). grid (98 f-tiles, 8 b).
// ---------------------------------------------------------------------------
__global__ __launch_bounds__(256)
void k3_fused(const ushort* __restrict__ xb16, const ushort* __restrict__ ab,
              float* __restrict__ out) {
    __shared__ ushort Bs[2][64 * 72];    // 2 x 9 KB

    const int t    = threadIdx.x;
    const int f0   = blockIdx.x * 64;
    const int b    = blockIdx.y;
    const int wv   = t >> 6;
    const int lane = t & 63;
    const int n16  = lane & 15;
    const int quad = lane >> 4;
    const int g    = t >> 4;             // f-quad 0..15
    const int kp   = t & 15;             // k-pair slot 0..15 (handles kp, kp+16)

    const ushort* xb  = xb16 + (size_t)b * LQ * FDIM + f0 + 4 * g;
    const ushort* abb = ab   + (size_t)b * LQ * LQ;

    f32x4 acc[4][4];
    #pragma unroll
    for (int mf = 0; mf < 4; ++mf)
        #pragma unroll
        for (int nf = 0; nf < 4; ++nf)
            acc[mf][nf] = (f32x4){0.f, 0.f, 0.f, 0.f};

    uint2 r0, r1, r2, r3;                // rows 2kp, 2kp+1, 2kp+32, 2kp+33
#define LDX(kc) do {                                                      \
        r0 = *(const uint2*)(xb + (size_t)((kc) + 2 * kp     ) * FDIM);   \
        r1 = *(const uint2*)(xb + (size_t)((kc) + 2 * kp +  1) * FDIM);   \
        r2 = *(const uint2*)(xb + (size_t)((kc) + 2 * kp + 32) * FDIM);   \
        r3 = *(const uint2*)(xb + (size_t)((kc) + 2 * kp + 33) * FDIM);   \
    } while (0)
    // word(f=4g+j, slot) = lo16(rowA[j]) | hi16<-lo16(rowB[j])
#define STX(bufi) do {                                                    \
        unsigned* bw = (unsigned*)(Bs[bufi]);                             \
        bw[(4 * g + 0) * 36 + kp]      = (r0.x & 0xffffu) | (r1.x << 16); \
        bw[(4 * g + 1) * 36 + kp]      = (r0.x >> 16) | (r1.x & 0xffff0000u); \
        bw[(4 * g + 2) * 36 + kp]      = (r0.y & 0xffffu) | (r1.y << 16); \
        bw[(4 * g + 3) * 36 + kp]      = (r0.y >> 16) | (r1.y & 0xffff0000u); \
        bw[(4 * g + 0) * 36 + kp + 16] = (r2.x & 0xffffu) | (r3.x << 16); \
        bw[(4 * g + 1) * 36 + kp + 16] = (r2.x >> 16) | (r3.x & 0xffff0000u); \
        bw[(4 * g + 2) * 36 + kp + 16] = (r2.y & 0xffffu) | (r3.y << 16); \
        bw[(4 * g + 3) * 36 + kp + 16] = (r2.y >> 16) | (r3.y & 0xffff0000u); \
    } while (0)

    LDX(0);
    STX(0);

    for (int c = 0; c < 4; ++c) {
        if (c < 3) LDX((c + 1) * 64);          // prefetch next x-chunk
        short8 af[4][2];                       // A-frags (global, L2-hot)
        #pragma unroll
        for (int mf = 0; mf < 4; ++mf)
            #pragma unroll
            for (int h = 0; h < 2; ++h)
                af[mf][h] = *(const short8*)(abb
                    + (size_t)(64 * wv + 16 * mf + n16) * LQ
                    + c * 64 + h * 32 + quad * 8);
        __syncthreads();                       // Bs[c&1] ready; prev reads done
        const ushort* bsc = Bs[c & 1];
        #pragma unroll
        for (int h = 0; h < 2; ++h)
            #pragma unroll
            for (int nf = 0; nf < 4; ++nf) {
                const short8 bf = *(const short8*)(bsc + (16 * nf + n16) * 72
                                                   + h * 32 + quad * 8);
                #pragma unroll
                for (int mf = 0; mf < 4; ++mf)
                    acc[mf][nf] = __builtin_amdgcn_mfma_f32_16x16x32_bf16(
                        af[mf][h], bf, acc[mf][nf], 0, 0, 0);
            }
        if (c < 3) STX((c + 1) & 1);           // fill the other buffer
    }
#undef LDX
#undef STX

    float* ob = out + ((size_t)b * LQ + 64 * wv + quad * 4) * FDIM + f0 + n16;
    #pragma unroll
    for (int mf = 0; mf < 4; ++mf)
        #pragma unroll
        for (int nf = 0; nf < 4; ++nf)
            #pragma unroll
            for (int r = 0; r < 4; ++r)
                ob[(size_t)(16 * mf + r) * FDIM + 16 * nf] = acc[mf][nf][r];
}

// ---------------------------------------------------------------------------
extern "C" void kernel_launch(void* const* d_in, const int* in_sizes, int n_in,
                              void* d_out, int out_size, void* d_ws, size_t ws_size,
                              hipStream_t stream) {
    const float* x  = (const float*)d_in[0];   // [8,256,6272]
    const float* Wt = (const float*)d_in[1];   // [6272,32]
    const float* bh = (const float*)d_in[2];   // [32]
    const float* Wa = (const float*)d_in[3];   // [32,1]
    const float* ba = (const float*)d_in[4];   // [1]
    float* out = (float*)d_out;                // [8,256,6272]

    float*  pbp  = (float*)d_ws;                               // 7*2048*32 fp32 (1.75 MB, pad 2M)
    ushort* ab   = (ushort*)((char*)d_ws + 2097152);           // 8*256*256 bf16 (1 MB)
    ushort* xb16 = (ushort*)((char*)d_ws + 2097152 + 1048576); // 8*256*6272 bf16 (25.7 MB)

    k1_mfma<<<dim3(64, 7), 256, 0, stream>>>(x, Wt, pbp, xb16);
    k2_attn<<<512, 256, 0, stream>>>(pbp, bh, Wa, ba, ab);
    k3_fused<<<dim3(98, 8), 256, 0, stream>>>(xb16, ab, out);
}

// Round 2
// 156.687 us; speedup vs baseline: 1.0354x; 1.0290x over previous
//
#include <hip/hip_runtime.h>
#include <hip/hip_bf16.h>
#include <math.h>

#define FDIM 6272
#define LQ   256
#define BN   8
#define UDIM 32
#define BL   (BN*LQ)        // 2048
#define FSPL 448            // f-columns per k1 split
#define NSPL 14             // number of f-splits (448*14 = 6272)
#define WTS2 456            // LDS f-stride for staged Wt (912B = 57x16B, odd multiple -> b128 frags <=2-way)

typedef short  short8 __attribute__((ext_vector_type(8)));
typedef float  f32x4  __attribute__((ext_vector_type(4)));

static __device__ __forceinline__ ushort f2bf(float f) {
    __hip_bfloat16 h = __float2bfloat16(f);
    return *(ushort*)&h;
}
// raw transcendentals (v_exp_f32 = 2^x); s_nop covers the TRANS-op hazard
static __device__ __forceinline__ float fexp2(float x) {
    float r;
    asm volatile("v_exp_f32 %0, %1 \n s_nop 1" : "=v"(r) : "v"(x));
    return r;
}
static __device__ __forceinline__ float frcp(float x) {
    float r;
    asm volatile("v_rcp_f32 %0, %1 \n s_nop 1" : "=v"(r) : "v"(x));
    return r;
}
static __device__ __forceinline__ float tanh_fast(float v) {
    // tanh(v) = 1 - 2/(1 + 2^(2v/ln2))
    return 1.f - 2.f * frcp(1.f + fexp2(v * 2.88539008177793f));
}

// ---------------------------------------------------------------------------
// K1: split-K p = x @ Wt, bf16 MFMA. Each wave owns 16 UNIQUE rows and
// computes BOTH u-halves (2 B-frags from LDS, 2 accs) -> every x element
// read exactly once per block (halves the old dup-read traffic). Wt staged
// per-block into LDS bf16 [u][f_local], stride 456 ushorts. Each (bx,by)
// block writes its f-split partial to pbp[by] with plain stores (no
// atomics, no pre-zero, poison-safe). Byproduct: packed A-frags stored as
// xb16[row][f] for K3 (each element exactly once). grid (32 row-tiles, 14
// f-splits), block 256 = 4 waves x 16 rows.
// ---------------------------------------------------------------------------
__global__ __launch_bounds__(256)
void k1_mfma(const float* __restrict__ x, const float* __restrict__ Wt,
             float* __restrict__ pbp, ushort* __restrict__ xb16) {
    __shared__ ushort wtt_s[UDIM * WTS2];   // 28.5 KB

    const int t  = threadIdx.x;
    const int f0 = blockIdx.y * FSPL;

    // --- stage Wt[f0..f0+448][0..32] -> wtt_s[u][f_local] as bf16 ---
    // wave reads 8 full 128B Wt rows per step (fully coalesced, L2-hot)
    {
        const int fl0 = t >> 3;          // 0..31 : f row within step
        const int u4  = (t & 7) * 4;     // 0,4,...,28 : u quad
        #pragma unroll
        for (int s = 0; s < NSPL; ++s) {
            const int fl = s * 32 + fl0;
            const float4 w4 = *(const float4*)(Wt + (size_t)(f0 + fl) * UDIM + u4);
            wtt_s[(u4 + 0) * WTS2 + fl] = f2bf(w4.x);
            wtt_s[(u4 + 1) * WTS2 + fl] = f2bf(w4.y);
            wtt_s[(u4 + 2) * WTS2 + fl] = f2bf(w4.z);
            wtt_s[(u4 + 3) * WTS2 + fl] = f2bf(w4.w);
        }
    }
    __syncthreads();

    const int wv   = t >> 6, lane = t & 63;
    const int n16  = lane & 15, quad = lane >> 4;
    const int row0 = blockIdx.x * 64 + 16 * wv;   // 16 unique rows per wave

    const float*  xr  = x + (size_t)(row0 + n16) * FDIM + f0 + quad * 8;
    const ushort* wr0 = wtt_s + (     n16) * WTS2 + quad * 8;   // u 0..15
    const ushort* wr1 = wtt_s + (16 + n16) * WTS2 + quad * 8;   // u 16..31
    ushort*       xw  = xb16 + (size_t)(row0 + n16) * FDIM + f0 + quad * 8;

    f32x4 acc0 = (f32x4){0.f, 0.f, 0.f, 0.f};
    f32x4 acc1 = (f32x4){0.f, 0.f, 0.f, 0.f};

    #pragma unroll 7
    for (int c = 0; c < NSPL; ++c) {
        const float4 a0 = *(const float4*)(xr + c * 32);
        const float4 a1 = *(const float4*)(xr + c * 32 + 4);
        short8 af;
        af[0] = (short)f2bf(a0.x); af[1] = (short)f2bf(a0.y);
        af[2] = (short)f2bf(a0.z); af[3] = (short)f2bf(a0.w);
        af[4] = (short)f2bf(a1.x); af[5] = (short)f2bf(a1.y);
        af[6] = (short)f2bf(a1.z); af[7] = (short)f2bf(a1.w);
        *(short8*)(xw + c * 32) = af;               // every row unique now
        const short8 b0 = *(const short8*)(wr0 + c * 32);  // ds_read_b128
        const short8 b1 = *(const short8*)(wr1 + c * 32);
        acc0 = __builtin_amdgcn_mfma_f32_16x16x32_bf16(af, b0, acc0, 0, 0, 0);
        acc1 = __builtin_amdgcn_mfma_f32_16x16x32_bf16(af, b1, acc1, 0, 0, 0);
    }

    // plain stores: pbp[by][row][u], each element written exactly once
    float* pb = pbp + (size_t)blockIdx.y * BL * UDIM;
    #pragma unroll
    for (int r = 0; r < 4; ++r) {
        pb[(size_t)(row0 + quad * 4 + r) * UDIM +      n16] = acc0[r];
        pb[(size_t)(row0 + quad * 4 + r) * UDIM + 16 + n16] = acc1[r];
    }
}

// ---------------------------------------------------------------------------
// K2: a[b,q,:] = softmax_k sigmoid( tanh(p_q+p_k+bh).Wa + ba ), fast-tanh.
// Sums the 14 split-K partials on load (float4, L2-hot), then amortizes the
// 32KB pk tile over 4 q-rows per block. grid 512 (8 b x 64 q-tiles).
// ---------------------------------------------------------------------------
__global__ __launch_bounds__(256)
void k2_attn(const float* __restrict__ pbp, const float* __restrict__ bh,
             const float* __restrict__ Wa, const float* __restrict__ ba,
             ushort* __restrict__ ab) {
    const int blk = blockIdx.x;
    const int b   = blk >> 6, qt = blk & 63;   // 4 q-rows per block
    const int k   = threadIdx.x;

    __shared__ float pk_s[LQ * 33];
    __shared__ float pq_s[4][UDIM];
    __shared__ float wa_s[UDIM];
    __shared__ float red[4][4];

    if (k < UDIM) wa_s[k] = Wa[k];
    const float* pbb = pbp + (size_t)b * LQ * UDIM;
    #pragma unroll
    for (int i = 0; i < 8; ++i) {              // sum 14 partials, float4
        const int e = 4 * k + 1024 * i;        // element in [0, 8192)
        float4 v = *(const float4*)(pbb + e);
        #pragma unroll
        for (int y = 1; y < NSPL; ++y) {
            const float4 p = *(const float4*)(pbb + (size_t)y * BL * UDIM + e);
            v.x += p.x; v.y += p.y; v.z += p.z; v.w += p.w;
        }
        float* d = &pk_s[(e >> 5) * 33 + (e & 31)];  // same 33-stride swizzle
        d[0] = v.x; d[1] = v.y; d[2] = v.z; d[3] = v.w;
    }
    __syncthreads();
    if (k < 4 * UDIM) {
        const int j = k >> 5, u = k & 31;
        pq_s[j][u] = pk_s[(qt * 4 + j) * 33 + u] + bh[u];
    }
    __syncthreads();

    // cache this thread's k-row once, reuse for 4 q's (32 VGPRs)
    const float* pk = &pk_s[k * 33];
    float pkr[UDIM];
    #pragma unroll
    for (int u = 0; u < UDIM; ++u) pkr[u] = pk[u];

    const float ba0 = ba[0];
    float e4[4];
    #pragma unroll
    for (int j = 0; j < 4; ++j) {
        float s = 0.f;
        #pragma unroll
        for (int u = 0; u < UDIM; ++u)
            s = fmaf(tanh_fast(pq_s[j][u] + pkr[u]), wa_s[u], s);

        const float alpha = frcp(1.f + fexp2(-(s + ba0) * 1.44269504088896f));
        const float e = fexp2(alpha * 1.44269504088896f);  // sigmoid in (0,1): safe
        e4[j] = e;

        float v = e;
        #pragma unroll
        for (int m = 1; m < 64; m <<= 1) v += __shfl_xor(v, m, 64);
        if ((k & 63) == 0) red[j][k >> 6] = v;
    }
    __syncthreads();
    #pragma unroll
    for (int j = 0; j < 4; ++j) {
        const float tot = red[j][0] + red[j][1] + red[j][2] + red[j][3];
        ab[((size_t)b * LQ + qt * 4 + j) * LQ + k] = f2bf(e4[j] * frcp(tot));
    }
}

// ---------------------------------------------------------------------------
// K3: out[b,q,f] = sum_k a[b,q,k]*x[b,k,f], bf16 MFMA, staging from xb16
// (bf16: half the fetch bytes, no v_cvt in repack). BK=64 double-
// buffered LDS, one barrier per chunk, prefetch in flight across barrier.
// A-frags direct from global (ab is L2-hot). Bs rows stride 72 ushort
// (9x16B, odd -> conflict-free b128 frags). grid (98 f-tiles, 8 b).
// ---------------------------------------------------------------------------
__global__ __launch_bounds__(256)
void k3_fused(const ushort* __restrict__ xb16, const ushort* __restrict__ ab,
              float* __restrict__ out) {
    __shared__ ushort Bs[2][64 * 72];    // 2 x 9 KB

    const int t    = threadIdx.x;
    const int f0   = blockIdx.x * 64;
    const int b    = blockIdx.y;
    const int wv   = t >> 6;
    const int lane = t & 63;
    const int n16  = lane & 15;
    const int quad = lane >> 4;
    const int g    = t >> 4;             // f-quad 0..15
    const int kp   = t & 15;             // k-pair slot 0..15 (handles kp, kp+16)

    const ushort* xb  = xb16 + (size_t)b * LQ * FDIM + f0 + 4 * g;
    const ushort* abb = ab   + (size_t)b * LQ * LQ;

    f32x4 acc[4][4];
    #pragma unroll
    for (int mf = 0; mf < 4; ++mf)
        #pragma unroll
        for (int nf = 0; nf < 4; ++nf)
            acc[mf][nf] = (f32x4){0.f, 0.f, 0.f, 0.f};

    uint2 r0, r1, r2, r3;                // rows 2kp, 2kp+1, 2kp+32, 2kp+33
#define LDX(kc) do {                                                      \
        r0 = *(const uint2*)(xb + (size_t)((kc) + 2 * kp     ) * FDIM);   \
        r1 = *(const uint2*)(xb + (size_t)((kc) + 2 * kp +  1) * FDIM);   \
        r2 = *(const uint2*)(xb + (size_t)((kc) + 2 * kp + 32) * FDIM);   \
        r3 = *(const uint2*)(xb + (size_t)((kc) + 2 * kp + 33) * FDIM);   \
    } while (0)
    // word(f=4g+j, slot) = lo16(rowA[j]) | hi16<-lo16(rowB[j])
#define STX(bufi) do {                                                    \
        unsigned* bw = (unsigned*)(Bs[bufi]);                             \
        bw[(4 * g + 0) * 36 + kp]      = (r0.x & 0xffffu) | (r1.x << 16); \
        bw[(4 * g + 1) * 36 + kp]      = (r0.x >> 16) | (r1.x & 0xffff0000u); \
        bw[(4 * g + 2) * 36 + kp]      = (r0.y & 0xffffu) | (r1.y << 16); \
        bw[(4 * g + 3) * 36 + kp]      = (r0.y >> 16) | (r1.y & 0xffff0000u); \
        bw[(4 * g + 0) * 36 + kp + 16] = (r2.x & 0xffffu) | (r3.x << 16); \
        bw[(4 * g + 1) * 36 + kp + 16] = (r2.x >> 16) | (r3.x & 0xffff0000u); \
        bw[(4 * g + 2) * 36 + kp + 16] = (r2.y & 0xffffu) | (r3.y << 16); \
        bw[(4 * g + 3) * 36 + kp + 16] = (r2.y >> 16) | (r3.y & 0xffff0000u); \
    } while (0)

    LDX(0);
    STX(0);

    for (int c = 0; c < 4; ++c) {
        if (c < 3) LDX((c + 1) * 64);          // prefetch next x-chunk
        short8 af[4][2];                       // A-frags (global, L2-hot)
        #pragma unroll
        for (int mf = 0; mf < 4; ++mf)
            #pragma unroll
            for (int h = 0; h < 2; ++h)
                af[mf][h] = *(const short8*)(abb
                    + (size_t)(64 * wv + 16 * mf + n16) * LQ
                    + c * 64 + h * 32 + quad * 8);
        __syncthreads();                       // Bs[c&1] ready; prev reads done
        const ushort* bsc = Bs[c & 1];
        #pragma unroll
        for (int h = 0; h < 2; ++h)
            #pragma unroll
            for (int nf = 0; nf < 4; ++nf) {
                const short8 bf = *(const short8*)(bsc + (16 * nf + n16) * 72
                                                   + h * 32 + quad * 8);
                #pragma unroll
                for (int mf = 0; mf < 4; ++mf)
                    acc[mf][nf] = __builtin_amdgcn_mfma_f32_16x16x32_bf16(
                        af[mf][h], bf, acc[mf][nf], 0, 0, 0);
            }
        if (c < 3) STX((c + 1) & 1);           // fill the other buffer
    }
#undef LDX
#undef STX

    float* ob = out + ((size_t)b * LQ + 64 * wv + quad * 4) * FDIM + f0 + n16;
    #pragma unroll
    for (int mf = 0; mf < 4; ++mf)
        #pragma unroll
        for (int nf = 0; nf < 4; ++nf)
            #pragma unroll
            for (int r = 0; r < 4; ++r)
                ob[(size_t)(16 * mf + r) * FDIM + 16 * nf] = acc[mf][nf][r];
}

// ---------------------------------------------------------------------------
extern "C" void kernel_launch(void* const* d_in, const int* in_sizes, int n_in,
                              void* d_out, int out_size, void* d_ws, size_t ws_size,
                              hipStream_t stream) {
    const float* x  = (const float*)d_in[0];   // [8,256,6272]
    const float* Wt = (const float*)d_in[1];   // [6272,32]
    const float* bh = (const float*)d_in[2];   // [32]
    const float* Wa = (const float*)d_in[3];   // [32,1]
    const float* ba = (const float*)d_in[4];   // [1]
    float* out = (float*)d_out;                // [8,256,6272]

    float*  pbp  = (float*)d_ws;                               // 14*2048*32 fp32 (3.67 MB, pad 4M)
    ushort* ab   = (ushort*)((char*)d_ws + 4194304);           // 8*256*256 bf16 (1 MB)
    ushort* xb16 = (ushort*)((char*)d_ws + 4194304 + 1048576); // 8*256*6272 bf16 (25.7 MB)

    k1_mfma<<<dim3(32, NSPL), 256, 0, stream>>>(x, Wt, pbp, xb16);
    k2_attn<<<512, 256, 0, stream>>>(pbp, bh, Wa, ba, ab);
    k3_fused<<<dim3(98, 8), 256, 0, stream>>>(xb16, ab, out);
}

// Round 3
// 152.328 us; speedup vs baseline: 1.0650x; 1.0286x over previous
//
#include <hip/hip_runtime.h>
#include <hip/hip_bf16.h>
#include <math.h>

#define FDIM 6272
#define LQ   256
#define BN   8
#define UDIM 32
#define BL   (BN*LQ)        // 2048
#define FSPL 448            // f-columns per k1 split
#define NSPL 14             // number of f-splits (448*14 = 6272)
#define WTS2 456            // LDS f-stride for staged Wt (912B = 57x16B, odd multiple -> b128 frags <=2-way)

typedef short  short8 __attribute__((ext_vector_type(8)));
typedef float  f32x4  __attribute__((ext_vector_type(4)));

static __device__ __forceinline__ ushort f2bf(float f) {
    __hip_bfloat16 h = __float2bfloat16(f);
    return *(ushort*)&h;
}
// raw transcendentals (v_exp_f32 = 2^x); s_nop covers the TRANS-op hazard
static __device__ __forceinline__ float fexp2(float x) {
    float r;
    asm volatile("v_exp_f32 %0, %1 \n s_nop 1" : "=v"(r) : "v"(x));
    return r;
}
static __device__ __forceinline__ float frcp(float x) {
    float r;
    asm volatile("v_rcp_f32 %0, %1 \n s_nop 1" : "=v"(r) : "v"(x));
    return r;
}
static __device__ __forceinline__ float tanh_fast(float v) {
    // tanh(v) = 1 - 2/(1 + 2^(2v/ln2))
    return 1.f - 2.f * frcp(1.f + fexp2(v * 2.88539008177793f));
}

// ---------------------------------------------------------------------------
// K1: split-K p = x @ Wt, bf16 MFMA. Each wave owns 16 UNIQUE rows and
// computes BOTH u-halves (2 B-frags from LDS, 2 accs) -> every x element
// read exactly once per block. Wt staged per-block into LDS bf16
// [u][f_local], stride 456 ushorts. Each (bx,by) block writes its f-split
// partial to pbp[by] with plain stores (no atomics, no pre-zero, poison-
// safe). xb16 byproduct REMOVED: k3 now stages from fp32 x via L3 hits,
// saving the 25.7MB dirty-writeback + a 16B store/lane/iter here.
// grid (32 row-tiles, 14 f-splits), block 256 = 4 waves x 16 rows.
// ---------------------------------------------------------------------------
__global__ __launch_bounds__(256)
void k1_mfma(const float* __restrict__ x, const float* __restrict__ Wt,
             float* __restrict__ pbp) {
    __shared__ ushort wtt_s[UDIM * WTS2];   // 28.5 KB

    const int t  = threadIdx.x;
    const int f0 = blockIdx.y * FSPL;

    // --- stage Wt[f0..f0+448][0..32] -> wtt_s[u][f_local] as bf16 ---
    // wave reads 8 full 128B Wt rows per step (fully coalesced, L2-hot)
    {
        const int fl0 = t >> 3;          // 0..31 : f row within step
        const int u4  = (t & 7) * 4;     // 0,4,...,28 : u quad
        #pragma unroll
        for (int s = 0; s < NSPL; ++s) {
            const int fl = s * 32 + fl0;
            const float4 w4 = *(const float4*)(Wt + (size_t)(f0 + fl) * UDIM + u4);
            wtt_s[(u4 + 0) * WTS2 + fl] = f2bf(w4.x);
            wtt_s[(u4 + 1) * WTS2 + fl] = f2bf(w4.y);
            wtt_s[(u4 + 2) * WTS2 + fl] = f2bf(w4.z);
            wtt_s[(u4 + 3) * WTS2 + fl] = f2bf(w4.w);
        }
    }
    __syncthreads();

    const int wv   = t >> 6, lane = t & 63;
    const int n16  = lane & 15, quad = lane >> 4;
    const int row0 = blockIdx.x * 64 + 16 * wv;   // 16 unique rows per wave

    const float*  xr  = x + (size_t)(row0 + n16) * FDIM + f0 + quad * 8;
    const ushort* wr0 = wtt_s + (     n16) * WTS2 + quad * 8;   // u 0..15
    const ushort* wr1 = wtt_s + (16 + n16) * WTS2 + quad * 8;   // u 16..31

    f32x4 acc0 = (f32x4){0.f, 0.f, 0.f, 0.f};
    f32x4 acc1 = (f32x4){0.f, 0.f, 0.f, 0.f};

    #pragma unroll 7
    for (int c = 0; c < NSPL; ++c) {
        const float4 a0 = *(const float4*)(xr + c * 32);
        const float4 a1 = *(const float4*)(xr + c * 32 + 4);
        short8 af;
        af[0] = (short)f2bf(a0.x); af[1] = (short)f2bf(a0.y);
        af[2] = (short)f2bf(a0.z); af[3] = (short)f2bf(a0.w);
        af[4] = (short)f2bf(a1.x); af[5] = (short)f2bf(a1.y);
        af[6] = (short)f2bf(a1.z); af[7] = (short)f2bf(a1.w);
        const short8 b0 = *(const short8*)(wr0 + c * 32);  // ds_read_b128
        const short8 b1 = *(const short8*)(wr1 + c * 32);
        acc0 = __builtin_amdgcn_mfma_f32_16x16x32_bf16(af, b0, acc0, 0, 0, 0);
        acc1 = __builtin_amdgcn_mfma_f32_16x16x32_bf16(af, b1, acc1, 0, 0, 0);
    }

    // plain stores: pbp[by][row][u], each element written exactly once
    float* pb = pbp + (size_t)blockIdx.y * BL * UDIM;
    #pragma unroll
    for (int r = 0; r < 4; ++r) {
        pb[(size_t)(row0 + quad * 4 + r) * UDIM +      n16] = acc0[r];
        pb[(size_t)(row0 + quad * 4 + r) * UDIM + 16 + n16] = acc1[r];
    }
}

// ---------------------------------------------------------------------------
// K2: a[b,q,:] = softmax_k sigmoid( tanh(p_q+p_k+bh).Wa + ba ), fast-tanh.
// Sums the 14 split-K partials on load (float4, L2/L3-hot), then amortizes
// the 33KB pk tile over 8 q-rows per block. grid 256 (8 b x 32 q-tiles)
// = exactly 1 block/CU; two accumulators break the serial fma chain.
// ---------------------------------------------------------------------------
__global__ __launch_bounds__(256)
void k2_attn(const float* __restrict__ pbp, const float* __restrict__ bh,
             const float* __restrict__ Wa, const float* __restrict__ ba,
             ushort* __restrict__ ab) {
    const int blk = blockIdx.x;
    const int b   = blk >> 5, qt = blk & 31;   // 8 q-rows per block
    const int k   = threadIdx.x;

    __shared__ float pk_s[LQ * 33];
    __shared__ float pq_s[8][UDIM];
    __shared__ float wa_s[UDIM];
    __shared__ float red[8][4];

    if (k < UDIM) wa_s[k] = Wa[k];
    const float* pbb = pbp + (size_t)b * LQ * UDIM;
    #pragma unroll
    for (int i = 0; i < 8; ++i) {              // sum 14 partials, float4
        const int e = 4 * k + 1024 * i;        // element in [0, 8192)
        float4 v = *(const float4*)(pbb + e);
        #pragma unroll
        for (int y = 1; y < NSPL; ++y) {
            const float4 p = *(const float4*)(pbb + (size_t)y * BL * UDIM + e);
            v.x += p.x; v.y += p.y; v.z += p.z; v.w += p.w;
        }
        float* d = &pk_s[(e >> 5) * 33 + (e & 31)];  // same 33-stride swizzle
        d[0] = v.x; d[1] = v.y; d[2] = v.z; d[3] = v.w;
    }
    __syncthreads();
    {
        const int j = k >> 5, u = k & 31;      // 256 threads = 8 rows x 32 u
        pq_s[j][u] = pk_s[(qt * 8 + j) * 33 + u] + bh[u];
    }
    __syncthreads();

    // cache this thread's k-row once, reuse for 8 q's (32 VGPRs)
    const float* pk = &pk_s[k * 33];
    float pkr[UDIM];
    #pragma unroll
    for (int u = 0; u < UDIM; ++u) pkr[u] = pk[u];

    const float ba0 = ba[0];
    float e8[8];
    #pragma unroll
    for (int j = 0; j < 8; ++j) {
        float s0 = 0.f, s1 = 0.f;              // 2 chains: hide fma latency
        #pragma unroll
        for (int u = 0; u < UDIM; u += 2) {
            s0 = fmaf(tanh_fast(pq_s[j][u    ] + pkr[u    ]), wa_s[u    ], s0);
            s1 = fmaf(tanh_fast(pq_s[j][u + 1] + pkr[u + 1]), wa_s[u + 1], s1);
        }
        const float s = s0 + s1;

        const float alpha = frcp(1.f + fexp2(-(s + ba0) * 1.44269504088896f));
        const float e = fexp2(alpha * 1.44269504088896f);  // sigmoid in (0,1): safe
        e8[j] = e;

        float v = e;
        #pragma unroll
        for (int m = 1; m < 64; m <<= 1) v += __shfl_xor(v, m, 64);
        if ((k & 63) == 0) red[j][k >> 6] = v;
    }
    __syncthreads();
    #pragma unroll
    for (int j = 0; j < 8; ++j) {
        const float tot = red[j][0] + red[j][1] + red[j][2] + red[j][3];
        ab[((size_t)b * LQ + qt * 8 + j) * LQ + k] = f2bf(e8[j] * frcp(tot));
    }
}

// ---------------------------------------------------------------------------
// K3: out[b,q,f] = sum_k a[b,q,k]*x[b,k,f], bf16 MFMA. Stages DIRECTLY
// from fp32 x (L3-resident after k1 read it in full) -> no xb16 round
// trip; f32->bf16 conversion fused into the LDS repack (bit-identical to
// the old k1-stored values). BK=64 double-buffered LDS, one barrier per
// chunk, prefetch in flight across barrier. A-frags direct from global
// (ab is L2-hot). Bs rows stride 72 ushort (9x16B, odd -> conflict-free
// b128 frags). grid (98 f-tiles, 8 b).
// ---------------------------------------------------------------------------
__global__ __launch_bounds__(256)
void k3_fused(const float* __restrict__ x, const ushort* __restrict__ ab,
              float* __restrict__ out) {
    __shared__ ushort Bs[2][64 * 72];    // 2 x 9 KB

    const int t    = threadIdx.x;
    const int f0   = blockIdx.x * 64;
    const int b    = blockIdx.y;
    const int wv   = t >> 6;
    const int lane = t & 63;
    const int n16  = lane & 15;
    const int quad = lane >> 4;
    const int g    = t >> 4;             // f-quad 0..15
    const int kp   = t & 15;             // k-pair slot 0..15 (handles kp, kp+16)

    const float*  xb  = x  + (size_t)b * LQ * FDIM + f0 + 4 * g;
    const ushort* abb = ab + (size_t)b * LQ * LQ;

    f32x4 acc[4][4];
    #pragma unroll
    for (int mf = 0; mf < 4; ++mf)
        #pragma unroll
        for (int nf = 0; nf < 4; ++nf)
            acc[mf][nf] = (f32x4){0.f, 0.f, 0.f, 0.f};

    float4 r0, r1, r2, r3;               // rows 2kp, 2kp+1, 2kp+32, 2kp+33
#define LDX(kc) do {                                                      \
        r0 = *(const float4*)(xb + (size_t)((kc) + 2 * kp     ) * FDIM);  \
        r1 = *(const float4*)(xb + (size_t)((kc) + 2 * kp +  1) * FDIM);  \
        r2 = *(const float4*)(xb + (size_t)((kc) + 2 * kp + 32) * FDIM);  \
        r3 = *(const float4*)(xb + (size_t)((kc) + 2 * kp + 33) * FDIM);  \
    } while (0)
    // word(f=4g+j, slot) = bf16(rowA[j]) | bf16(rowB[j])<<16
#define STX(bufi) do {                                                        \
        unsigned* bw = (unsigned*)(Bs[bufi]);                                 \
        bw[(4 * g + 0) * 36 + kp]      = (unsigned)f2bf(r0.x) | ((unsigned)f2bf(r1.x) << 16); \
        bw[(4 * g + 1) * 36 + kp]      = (unsigned)f2bf(r0.y) | ((unsigned)f2bf(r1.y) << 16); \
        bw[(4 * g + 2) * 36 + kp]      = (unsigned)f2bf(r0.z) | ((unsigned)f2bf(r1.z) << 16); \
        bw[(4 * g + 3) * 36 + kp]      = (unsigned)f2bf(r0.w) | ((unsigned)f2bf(r1.w) << 16); \
        bw[(4 * g + 0) * 36 + kp + 16] = (unsigned)f2bf(r2.x) | ((unsigned)f2bf(r3.x) << 16); \
        bw[(4 * g + 1) * 36 + kp + 16] = (unsigned)f2bf(r2.y) | ((unsigned)f2bf(r3.y) << 16); \
        bw[(4 * g + 2) * 36 + kp + 16] = (unsigned)f2bf(r2.z) | ((unsigned)f2bf(r3.z) << 16); \
        bw[(4 * g + 3) * 36 + kp + 16] = (unsigned)f2bf(r2.w) | ((unsigned)f2bf(r3.w) << 16); \
    } while (0)

    LDX(0);
    STX(0);

    for (int c = 0; c < 4; ++c) {
        if (c < 3) LDX((c + 1) * 64);          // prefetch next x-chunk
        short8 af[4][2];                       // A-frags (global, L2-hot)
        #pragma unroll
        for (int mf = 0; mf < 4; ++mf)
            #pragma unroll
            for (int h = 0; h < 2; ++h)
                af[mf][h] = *(const short8*)(abb
                    + (size_t)(64 * wv + 16 * mf + n16) * LQ
                    + c * 64 + h * 32 + quad * 8);
        __syncthreads();                       // Bs[c&1] ready; prev reads done
        const ushort* bsc = Bs[c & 1];
        #pragma unroll
        for (int h = 0; h < 2; ++h)
            #pragma unroll
            for (int nf = 0; nf < 4; ++nf) {
                const short8 bf = *(const short8*)(bsc + (16 * nf + n16) * 72
                                                   + h * 32 + quad * 8);
                #pragma unroll
                for (int mf = 0; mf < 4; ++mf)
                    acc[mf][nf] = __builtin_amdgcn_mfma_f32_16x16x32_bf16(
                        af[mf][h], bf, acc[mf][nf], 0, 0, 0);
            }
        if (c < 3) STX((c + 1) & 1);           // fill the other buffer
    }
#undef LDX
#undef STX

    float* ob = out + ((size_t)b * LQ + 64 * wv + quad * 4) * FDIM + f0 + n16;
    #pragma unroll
    for (int mf = 0; mf < 4; ++mf)
        #pragma unroll
        for (int nf = 0; nf < 4; ++nf)
            #pragma unroll
            for (int r = 0; r < 4; ++r)
                ob[(size_t)(16 * mf + r) * FDIM + 16 * nf] = acc[mf][nf][r];
}

// ---------------------------------------------------------------------------
extern "C" void kernel_launch(void* const* d_in, const int* in_sizes, int n_in,
                              void* d_out, int out_size, void* d_ws, size_t ws_size,
                              hipStream_t stream) {
    const float* x  = (const float*)d_in[0];   // [8,256,6272]
    const float* Wt = (const float*)d_in[1];   // [6272,32]
    const float* bh = (const float*)d_in[2];   // [32]
    const float* Wa = (const float*)d_in[3];   // [32,1]
    const float* ba = (const float*)d_in[4];   // [1]
    float* out = (float*)d_out;                // [8,256,6272]

    float*  pbp = (float*)d_ws;                      // 14*2048*32 fp32 (3.67 MB, pad 4M)
    ushort* ab  = (ushort*)((char*)d_ws + 4194304);  // 8*256*256 bf16 (1 MB)

    k1_mfma<<<dim3(32, NSPL), 256, 0, stream>>>(x, Wt, pbp);
    k2_attn<<<256, 256, 0, stream>>>(pbp, bh, Wa, ba, ab);
    k3_fused<<<dim3(98, 8), 256, 0, stream>>>(x, ab, out);
}

// Round 4
// 144.447 us; speedup vs baseline: 1.1231x; 1.0546x over previous
//
#include <hip/hip_runtime.h>
#include <hip/hip_bf16.h>
#include <math.h>

#define FDIM 6272
#define LQ   256
#define BN   8
#define UDIM 32
#define BL   (BN*LQ)        // 2048
#define FSPL 448            // f-columns per k1 split
#define NSPL 14             // number of f-splits (448*14 = 6272)
#define WTS2 456            // LDS f-stride for staged Wt (912B = 57x16B, odd multiple -> b128 frags <=2-way)

typedef short  short8 __attribute__((ext_vector_type(8)));
typedef float  f32x4  __attribute__((ext_vector_type(4)));

static __device__ __forceinline__ ushort f2bf(float f) {
    __hip_bfloat16 h = __float2bfloat16(f);
    return *(ushort*)&h;
}
// raw transcendentals (v_exp_f32 = 2^x); s_nop covers the TRANS-op hazard
static __device__ __forceinline__ float fexp2(float x) {
    float r;
    asm volatile("v_exp_f32 %0, %1 \n s_nop 1" : "=v"(r) : "v"(x));
    return r;
}
static __device__ __forceinline__ float frcp(float x) {
    float r;
    asm volatile("v_rcp_f32 %0, %1 \n s_nop 1" : "=v"(r) : "v"(x));
    return r;
}
static __device__ __forceinline__ float tanh_fast(float v) {
    // tanh(v) = 1 - 2/(1 + 2^(2v/ln2))
    return 1.f - 2.f * frcp(1.f + fexp2(v * 2.88539008177793f));
}

// ---------------------------------------------------------------------------
// K1: split-K p = x @ Wt, bf16 MFMA. Each wave owns 16 UNIQUE rows and
// computes BOTH u-halves (2 B-frags from LDS, 2 accs) -> every x element
// read exactly once per block. Wt staged per-block into LDS bf16
// [u][f_local], stride 456 ushorts. Each (bx,by) block writes its f-split
// partial to pbp[by] with plain stores (no atomics, no pre-zero, poison-
// safe). grid (32 row-tiles, 14 f-splits), block 256 = 4 waves x 16 rows.
// ---------------------------------------------------------------------------
__global__ __launch_bounds__(256)
void k1_mfma(const float* __restrict__ x, const float* __restrict__ Wt,
             float* __restrict__ pbp) {
    __shared__ ushort wtt_s[UDIM * WTS2];   // 28.5 KB

    const int t  = threadIdx.x;
    const int f0 = blockIdx.y * FSPL;

    // --- stage Wt[f0..f0+448][0..32] -> wtt_s[u][f_local] as bf16 ---
    // wave reads 8 full 128B Wt rows per step (fully coalesced, L2-hot)
    {
        const int fl0 = t >> 3;          // 0..31 : f row within step
        const int u4  = (t & 7) * 4;     // 0,4,...,28 : u quad
        #pragma unroll
        for (int s = 0; s < NSPL; ++s) {
            const int fl = s * 32 + fl0;
            const float4 w4 = *(const float4*)(Wt + (size_t)(f0 + fl) * UDIM + u4);
            wtt_s[(u4 + 0) * WTS2 + fl] = f2bf(w4.x);
            wtt_s[(u4 + 1) * WTS2 + fl] = f2bf(w4.y);
            wtt_s[(u4 + 2) * WTS2 + fl] = f2bf(w4.z);
            wtt_s[(u4 + 3) * WTS2 + fl] = f2bf(w4.w);
        }
    }
    __syncthreads();

    const int wv   = t >> 6, lane = t & 63;
    const int n16  = lane & 15, quad = lane >> 4;
    const int row0 = blockIdx.x * 64 + 16 * wv;   // 16 unique rows per wave

    const float*  xr  = x + (size_t)(row0 + n16) * FDIM + f0 + quad * 8;
    const ushort* wr0 = wtt_s + (     n16) * WTS2 + quad * 8;   // u 0..15
    const ushort* wr1 = wtt_s + (16 + n16) * WTS2 + quad * 8;   // u 16..31

    f32x4 acc0 = (f32x4){0.f, 0.f, 0.f, 0.f};
    f32x4 acc1 = (f32x4){0.f, 0.f, 0.f, 0.f};

    #pragma unroll 7
    for (int c = 0; c < NSPL; ++c) {
        const float4 a0 = *(const float4*)(xr + c * 32);
        const float4 a1 = *(const float4*)(xr + c * 32 + 4);
        short8 af;
        af[0] = (short)f2bf(a0.x); af[1] = (short)f2bf(a0.y);
        af[2] = (short)f2bf(a0.z); af[3] = (short)f2bf(a0.w);
        af[4] = (short)f2bf(a1.x); af[5] = (short)f2bf(a1.y);
        af[6] = (short)f2bf(a1.z); af[7] = (short)f2bf(a1.w);
        const short8 b0 = *(const short8*)(wr0 + c * 32);  // ds_read_b128
        const short8 b1 = *(const short8*)(wr1 + c * 32);
        acc0 = __builtin_amdgcn_mfma_f32_16x16x32_bf16(af, b0, acc0, 0, 0, 0);
        acc1 = __builtin_amdgcn_mfma_f32_16x16x32_bf16(af, b1, acc1, 0, 0, 0);
    }

    // plain stores: pbp[by][row][u], each element written exactly once
    float* pb = pbp + (size_t)blockIdx.y * BL * UDIM;
    #pragma unroll
    for (int r = 0; r < 4; ++r) {
        pb[(size_t)(row0 + quad * 4 + r) * UDIM +      n16] = acc0[r];
        pb[(size_t)(row0 + quad * 4 + r) * UDIM + 16 + n16] = acc1[r];
    }
}

// ---------------------------------------------------------------------------
// K2: a[b,q,:] = softmax_k sigmoid( tanh(p_q+p_k+bh).Wa + ba ), fast-tanh.
// Sums the 14 split-K partials on load (float4, L2/L3-hot), then amortizes
// the 33KB pk tile over 8 q-rows per block. 512 threads/block: thread-half
// h handles q-rows 4h..4h+3 for its key kk = t&255 -> 2 waves/SIMD so the
// TRANS-heavy tanh chain and the partial-restage latency interleave across
// waves (was 1 wave/SIMD). Arithmetic & reduction order bit-identical.
// grid 256 (8 b x 32 q-tiles).
// ---------------------------------------------------------------------------
__global__ __launch_bounds__(512)
void k2_attn(const float* __restrict__ pbp, const float* __restrict__ bh,
             const float* __restrict__ Wa, const float* __restrict__ ba,
             ushort* __restrict__ ab) {
    const int blk = blockIdx.x;
    const int b   = blk >> 5, qt = blk & 31;   // 8 q-rows per block
    const int t   = threadIdx.x;               // 0..511
    const int kk  = t & 255;                   // key index
    const int h   = t >> 8;                    // q-half 0/1

    __shared__ float pk_s[LQ * 33];
    __shared__ float pq_s[8][UDIM];
    __shared__ float wa_s[UDIM];
    __shared__ float red[8][4];

    if (t < UDIM) wa_s[t] = Wa[t];
    const float* pbb = pbp + (size_t)b * LQ * UDIM;
    #pragma unroll
    for (int i = 0; i < 4; ++i) {              // sum 14 partials, float4
        const int e = 4 * t + 2048 * i;        // element in [0, 8192)
        float4 v = *(const float4*)(pbb + e);
        #pragma unroll
        for (int y = 1; y < NSPL; ++y) {
            const float4 p = *(const float4*)(pbb + (size_t)y * BL * UDIM + e);
            v.x += p.x; v.y += p.y; v.z += p.z; v.w += p.w;
        }
        float* d = &pk_s[(e >> 5) * 33 + (e & 31)];  // same 33-stride swizzle
        d[0] = v.x; d[1] = v.y; d[2] = v.z; d[3] = v.w;
    }
    __syncthreads();
    if (t < 8 * UDIM) {
        const int j = t >> 5, u = t & 31;      // 256 threads = 8 rows x 32 u
        pq_s[j][u] = pk_s[(qt * 8 + j) * 33 + u] + bh[u];
    }
    __syncthreads();

    // cache this thread's k-row once, reuse for 4 q's (32 VGPRs)
    const float* pk = &pk_s[kk * 33];
    float pkr[UDIM];
    #pragma unroll
    for (int u = 0; u < UDIM; ++u) pkr[u] = pk[u];

    const float ba0 = ba[0];
    float e4[4];
    #pragma unroll
    for (int jj = 0; jj < 4; ++jj) {
        const int j = 4 * h + jj;
        float s0 = 0.f, s1 = 0.f;              // 2 chains: hide fma latency
        #pragma unroll
        for (int u = 0; u < UDIM; u += 2) {
            s0 = fmaf(tanh_fast(pq_s[j][u    ] + pkr[u    ]), wa_s[u    ], s0);
            s1 = fmaf(tanh_fast(pq_s[j][u + 1] + pkr[u + 1]), wa_s[u + 1], s1);
        }
        const float s = s0 + s1;

        const float alpha = frcp(1.f + fexp2(-(s + ba0) * 1.44269504088896f));
        const float e = fexp2(alpha * 1.44269504088896f);  // sigmoid in (0,1): safe
        e4[jj] = e;

        float v = e;
        #pragma unroll
        for (int m = 1; m < 64; m <<= 1) v += __shfl_xor(v, m, 64);
        if ((kk & 63) == 0) red[j][kk >> 6] = v;   // lane 0 of each wave
    }
    __syncthreads();
    #pragma unroll
    for (int jj = 0; jj < 4; ++jj) {
        const int j = 4 * h + jj;
        const float tot = red[j][0] + red[j][1] + red[j][2] + red[j][3];
        ab[((size_t)b * LQ + qt * 8 + j) * LQ + kk] = f2bf(e4[jj] * frcp(tot));
    }
}

// ---------------------------------------------------------------------------
// K3: out[b,q,f] = sum_k a[b,q,k]*x[b,k,f], bf16 MFMA. Stages DIRECTLY
// from fp32 x (L3-resident after k1); f32->bf16 fused into the LDS repack.
// BK=64 double-buffered LDS. Per-chunk sync is now writer-side-only:
// s_waitcnt lgkmcnt(0) + raw s_barrier (NO vmcnt(0) drain -> LDX/af
// prefetches stay in flight across the barrier; compiler emits counted
// vmcnt before their uses). Buffer discipline: chunk c reads Bs[c&1];
// STX in chunk c writes Bs[(c+1)&1]; Bs[c&1] is only overwritten after
// barrier(c+1), by which point chunk c's reads are complete. A-frags
// direct from global (ab L2-hot). Bs rows stride 72 ushort (9x16B, odd
// -> conflict-free b128 frags). grid (98 f-tiles, 8 b).
// ---------------------------------------------------------------------------
__global__ __launch_bounds__(256)
void k3_fused(const float* __restrict__ x, const ushort* __restrict__ ab,
              float* __restrict__ out) {
    __shared__ ushort Bs[2][64 * 72];    // 2 x 9 KB

    const int t    = threadIdx.x;
    const int f0   = blockIdx.x * 64;
    const int b    = blockIdx.y;
    const int wv   = t >> 6;
    const int lane = t & 63;
    const int n16  = lane & 15;
    const int quad = lane >> 4;
    const int g    = t >> 4;             // f-quad 0..15
    const int kp   = t & 15;             // k-pair slot 0..15 (handles kp, kp+16)

    const float*  xb  = x  + (size_t)b * LQ * FDIM + f0 + 4 * g;
    const ushort* abb = ab + (size_t)b * LQ * LQ;

    f32x4 acc[4][4];
    #pragma unroll
    for (int mf = 0; mf < 4; ++mf)
        #pragma unroll
        for (int nf = 0; nf < 4; ++nf)
            acc[mf][nf] = (f32x4){0.f, 0.f, 0.f, 0.f};

    float4 r0, r1, r2, r3;               // rows 2kp, 2kp+1, 2kp+32, 2kp+33
#define LDX(kc) do {                                                      \
        r0 = *(const float4*)(xb + (size_t)((kc) + 2 * kp     ) * FDIM);  \
        r1 = *(const float4*)(xb + (size_t)((kc) + 2 * kp +  1) * FDIM);  \
        r2 = *(const float4*)(xb + (size_t)((kc) + 2 * kp + 32) * FDIM);  \
        r3 = *(const float4*)(xb + (size_t)((kc) + 2 * kp + 33) * FDIM);  \
    } while (0)
    // word(f=4g+j, slot) = bf16(rowA[j]) | bf16(rowB[j])<<16
#define STX(bufi) do {                                                        \
        unsigned* bw = (unsigned*)(Bs[bufi]);                                 \
        bw[(4 * g + 0) * 36 + kp]      = (unsigned)f2bf(r0.x) | ((unsigned)f2bf(r1.x) << 16); \
        bw[(4 * g + 1) * 36 + kp]      = (unsigned)f2bf(r0.y) | ((unsigned)f2bf(r1.y) << 16); \
        bw[(4 * g + 2) * 36 + kp]      = (unsigned)f2bf(r0.z) | ((unsigned)f2bf(r1.z) << 16); \
        bw[(4 * g + 3) * 36 + kp]      = (unsigned)f2bf(r0.w) | ((unsigned)f2bf(r1.w) << 16); \
        bw[(4 * g + 0) * 36 + kp + 16] = (unsigned)f2bf(r2.x) | ((unsigned)f2bf(r3.x) << 16); \
        bw[(4 * g + 1) * 36 + kp + 16] = (unsigned)f2bf(r2.y) | ((unsigned)f2bf(r3.y) << 16); \
        bw[(4 * g + 2) * 36 + kp + 16] = (unsigned)f2bf(r2.z) | ((unsigned)f2bf(r3.z) << 16); \
        bw[(4 * g + 3) * 36 + kp + 16] = (unsigned)f2bf(r2.w) | ((unsigned)f2bf(r3.w) << 16); \
    } while (0)

    LDX(0);
    STX(0);

    #pragma unroll
    for (int c = 0; c < 4; ++c) {
        if (c < 3) LDX((c + 1) * 64);          // prefetch next x-chunk (stays in flight)
        short8 af[4][2];                       // A-frags (global, L2-hot)
        #pragma unroll
        for (int mf = 0; mf < 4; ++mf)
            #pragma unroll
            for (int h = 0; h < 2; ++h)
                af[mf][h] = *(const short8*)(abb
                    + (size_t)(64 * wv + 16 * mf + n16) * LQ
                    + c * 64 + h * 32 + quad * 8);
        // writer-side LDS visibility only: drain ds_writes, raw barrier.
        // No vmcnt drain -> LDX/af loads cross the barrier in flight.
        asm volatile("s_waitcnt lgkmcnt(0)" ::: "memory");
        __builtin_amdgcn_s_barrier();
        const ushort* bsc = Bs[c & 1];
        #pragma unroll
        for (int h = 0; h < 2; ++h)
            #pragma unroll
            for (int nf = 0; nf < 4; ++nf) {
                const short8 bf = *(const short8*)(bsc + (16 * nf + n16) * 72
                                                   + h * 32 + quad * 8);
                #pragma unroll
                for (int mf = 0; mf < 4; ++mf)
                    acc[mf][nf] = __builtin_amdgcn_mfma_f32_16x16x32_bf16(
                        af[mf][h], bf, acc[mf][nf], 0, 0, 0);
            }
        if (c < 3) STX((c + 1) & 1);           // fill the other buffer
    }
#undef LDX
#undef STX

    float* ob = out + ((size_t)b * LQ + 64 * wv + quad * 4) * FDIM + f0 + n16;
    #pragma unroll
    for (int mf = 0; mf < 4; ++mf)
        #pragma unroll
        for (int nf = 0; nf < 4; ++nf)
            #pragma unroll
            for (int r = 0; r < 4; ++r)
                ob[(size_t)(16 * mf + r) * FDIM + 16 * nf] = acc[mf][nf][r];
}

// ---------------------------------------------------------------------------
extern "C" void kernel_launch(void* const* d_in, const int* in_sizes, int n_in,
                              void* d_out, int out_size, void* d_ws, size_t ws_size,
                              hipStream_t stream) {
    const float* x  = (const float*)d_in[0];   // [8,256,6272]
    const float* Wt = (const float*)d_in[1];   // [6272,32]
    const float* bh = (const float*)d_in[2];   // [32]
    const float* Wa = (const float*)d_in[3];   // [32,1]
    const float* ba = (const float*)d_in[4];   // [1]
    float* out = (float*)d_out;                // [8,256,6272]

    float*  pbp = (float*)d_ws;                      // 14*2048*32 fp32 (3.67 MB, pad 4M)
    ushort* ab  = (ushort*)((char*)d_ws + 4194304);  // 8*256*256 bf16 (1 MB)

    k1_mfma<<<dim3(32, NSPL), 256, 0, stream>>>(x, Wt, pbp);
    k2_attn<<<256, 512, 0, stream>>>(pbp, bh, Wa, ba, ab);
    k3_fused<<<dim3(98, 8), 256, 0, stream>>>(x, ab, out);
}